// Round 8
// baseline (213.587 us; speedup 1.0000x reference)
//
#include <hip/hip_runtime.h>
#include <math.h>

#define NPTS 16384
#define KNB  16
#define D    512

// ---------------------------------------------------------------------------
// Closed-form restructure (verified rounds 1-7, absmax 0.0625). With
// S = gather-mean, R = Wres^T + I, M' = (W2c*W1)^T, per-block map
// f' = Cb + S^2 f M' + f R (f0 = 0), tracked in [33,512] coefficient space
// (rows 4k+c = component c of s_k, row 32 = bias):
//   F_1 = Cb33,   F_{t+1} = Cb33 + Shift2(F_t)*M' + F_t*R,   Ecat = F_4
// Final: out = [s0..s7,1] ([N,33]) x Ecat.
// Round 8: fp32 Mt/Rm (fp64 accumulate) halves fstep traffic; twohop at
// 32 thr/pt halves the scattered-load leaf burst; gather blocks dispatched
// before fstep blocks.
// ---------------------------------------------------------------------------

__device__ __forceinline__ float4 redN(float ax, float ay, float az, float aw,
                                       int width) {
#pragma unroll
  for (int o = 1; o < 32; o <<= 1) {
    if (o >= width) break;
    ax += __shfl_xor(ax, o, 64); ay += __shfl_xor(ay, o, 64);
    az += __shfl_xor(az, o, 64); aw += __shfl_xor(aw, o, 64);
  }
  return make_float4(ax, ay, az, aw);
}

// 1-hop gather-mean, 16 threads/point (t < 262144)
__device__ __forceinline__ void onehop16(int t, const int* __restrict__ knn,
                                         const float4* __restrict__ in,
                                         float4* __restrict__ out) {
  int n = t >> 4, k = t & 15;
  float4 g = in[knn[n * KNB + k]];
  float4 s = redN(g.x, g.y, g.z, g.w, 16);
  if (k == 0) {
    const float r = 1.f / 16.f;
    out[n] = make_float4(s.x * r, s.y * r, s.z * r, s.w * r);
  }
}

// 2-hop gather-mean, 32 threads/point (t < 524288): half an outer each
__device__ __forceinline__ void twohop32(int t, const int* __restrict__ knn,
                                         const float4* __restrict__ in,
                                         float4* __restrict__ out) {
  int n = t >> 5, l = t & 31, a = l >> 1, h = l & 1;
  int ia = knn[n * KNB + a];
  const int4* ip = (const int4*)(knn + ia * KNB) + 2 * h;  // 32B-aligned
  int4 i0 = ip[0], i1 = ip[1];
  float ax = 0.f, ay = 0.f, az = 0.f, aw = 0.f;
#define ACC(idx) { float4 g = in[idx]; ax += g.x; ay += g.y; az += g.z; aw += g.w; }
  ACC(i0.x) ACC(i0.y) ACC(i0.z) ACC(i0.w)
  ACC(i1.x) ACC(i1.y) ACC(i1.z) ACC(i1.w)
#undef ACC
  float4 s = redN(ax, ay, az, aw, 32);
  if (l == 0) {
    const float r = 1.f / 256.f;
    out[n] = make_float4(s.x * r, s.y * r, s.z * r, s.w * r);
  }
}

// One Horner step: Fnext[r][j] = cb(r,j) + sum_k Fprev[r][k]R[k][j]
//                               + sum_k Fprev[rm][k]M'[k][j]
// rm = r-8 (rows 8..31), 32 for bias row, none for rows 0..7.
// rb in [0,132): r = rb>>2, col-chunk = rb&3. 1024 thr: 128 cols x 8 k-chunks.
__device__ __forceinline__ void fstep_block(
    int rb, int tid, int first, const float* __restrict__ Fprev,
    const float* __restrict__ zbuf, const float* __restrict__ Rm,
    const float* __restrict__ Mt, float* __restrict__ Fnext) {
  __shared__ double sA[512], sB[512];
  __shared__ double red[8][128];
  const int r = rb >> 2, cchunk = rb & 3;
  const int rm = (r >= 8 && r < 32) ? (r - 8) : (r == 32 ? 32 : -1);
  if (tid < 512) {
    float v;
    if (first)
      v = (r < 8) ? zbuf[r * D + tid] : (r == 32 ? zbuf[8 * D + tid] : 0.f);
    else
      v = Fprev[r * D + tid];
    sA[tid] = (double)v;
  } else {
    int kk = tid - 512;
    float v = 0.f;
    if (rm >= 0) {
      if (first)
        v = (rm < 8) ? zbuf[rm * D + kk] : (rm == 32 ? zbuf[8 * D + kk] : 0.f);
      else
        v = Fprev[rm * D + kk];
    }
    sB[kk] = (double)v;
  }
  __syncthreads();
  const int col = tid & 127, kc = tid >> 7;
  const int j = cchunk * 128 + col, k0 = kc * 64;
  double a0 = 0.0, a1 = 0.0;
  for (int k = 0; k < 64; k += 2) {
    a0 += sA[k0 + k] * (double)Rm[(size_t)(k0 + k) * D + j] +
          sB[k0 + k] * (double)Mt[(size_t)(k0 + k) * D + j];
    a1 += sA[k0 + k + 1] * (double)Rm[(size_t)(k0 + k + 1) * D + j] +
          sB[k0 + k + 1] * (double)Mt[(size_t)(k0 + k + 1) * D + j];
  }
  red[kc][col] = a0 + a1;
  __syncthreads();
  if (kc == 0) {
    double s = 0.0;
#pragma unroll
    for (int u = 0; u < 8; ++u) s += red[u][col];
    float cb = (r < 8) ? zbuf[r * D + j] : (r == 32 ? zbuf[8 * D + j] : 0.f);
    Fnext[r * D + j] = (float)(s + (double)cb);
  }
}

// ---- L0: knn normalize | geo (16 thr/pt) | pq(z) | Mt | Rm ----
__global__ __launch_bounds__(256) void prep_kernel(
    const float* __restrict__ pts, const int* __restrict__ raw,
    const float* __restrict__ w_mlp1, const float* __restrict__ b_mlp1,
    const float* __restrict__ w_lfa1, const float* __restrict__ b_lfa1,
    const float* __restrict__ w_lfa2, const float* __restrict__ b_lfa2,
    const float* __restrict__ w_mlp2, const float* __restrict__ b_mlp2,
    const float* __restrict__ w_res, const float* __restrict__ b_res,
    int* __restrict__ knn_i, float4* __restrict__ sbase,
    float* __restrict__ zbuf, float* __restrict__ Mt,
    float* __restrict__ Rm) {
  // int64 little-endian => odd words are zero high halves; (1/16384)^4 FP risk
  const bool is64 = (raw[1] == 0) && (raw[3] == 0) && (raw[5] == 0) &&
                    (raw[7] == 0);
  const int t = blockIdx.x * 256 + threadIdx.x;  // < 262144 == D*D
  knn_i[t] = is64 ? raw[2 * t] : raw[t];
  {  // geo: 16 threads/point
    int n = t >> 4, k = t & 15;
    int idx = is64 ? raw[2 * (n * KNB + k)] : raw[n * KNB + k];
    float dx = pts[n * 3 + 0] - pts[idx * 3 + 0];
    float dy = pts[n * 3 + 1] - pts[idx * 3 + 1];
    float dz = pts[n * 3 + 2] - pts[idx * 3 + 2];
    float nr = sqrtf(dx * dx + dy * dy + dz * dz);
    float4 s = redN(dx, dy, dz, nr, 16);
    if (k == 0) {
      const float r = 1.f / 16.f;
      sbase[n] = make_float4(s.x * r, s.y * r, s.z * r, s.w * r);
    }
  }
  if (t < 32768) {  // pq: one wave per output column j; fp64 accumulate
    int j = t >> 6, lane = t & 63;
    const float* wrow = w_mlp2 + (size_t)j * D;
    double acc[9];
#pragma unroll
    for (int u = 0; u < 9; ++u) acc[u] = 0.0;
#pragma unroll
    for (int it = 0; it < 8; ++it) {
      int i = lane + 64 * it;
      double w = wrow[i];
      if (i < 256) {
        acc[0] += w * w_lfa2[i * 4 + 0]; acc[1] += w * w_lfa2[i * 4 + 1];
        acc[2] += w * w_lfa2[i * 4 + 2]; acc[3] += w * w_lfa2[i * 4 + 3];
        acc[8] += w * b_lfa2[i];
      } else if (i < 384) {
        int q = i - 256;
        acc[4] += w * w_lfa1[q * 4 + 0]; acc[5] += w * w_lfa1[q * 4 + 1];
        acc[6] += w * w_lfa1[q * 4 + 2]; acc[7] += w * w_lfa1[q * 4 + 3];
        acc[8] += w * b_lfa1[q];
      } else {
        acc[8] += w * b_mlp1[i - 384];
      }
    }
#pragma unroll
    for (int u = 0; u < 9; ++u) {
      double v = acc[u];
#pragma unroll
      for (int o = 32; o > 0; o >>= 1) v += __shfl_down(v, o, 64);
      if (lane == 0) {
        if (u == 8) v += (double)b_mlp2[j] + (double)b_res[j];
        zbuf[u * D + j] = (float)v;
      }
    }
  }
  {  // Mt[a*D+b] = sum_{i<128} w_mlp2[b][384+i]*w_mlp1[i][a]  (fp64 acc)
    int a = t & 511, b = t >> 9;
    const float* wrow = w_mlp2 + (size_t)b * D + 384;
    double s0 = 0.0, s1 = 0.0, s2 = 0.0, s3 = 0.0;
#pragma unroll 8
    for (int i = 0; i < 128; i += 4) {
      s0 += (double)wrow[i + 0] * (double)w_mlp1[(size_t)(i + 0) * D + a];
      s1 += (double)wrow[i + 1] * (double)w_mlp1[(size_t)(i + 1) * D + a];
      s2 += (double)wrow[i + 2] * (double)w_mlp1[(size_t)(i + 2) * D + a];
      s3 += (double)wrow[i + 3] * (double)w_mlp1[(size_t)(i + 3) * D + a];
    }
    Mt[(size_t)a * D + b] = (float)((s0 + s1) + (s2 + s3));
  }
  {  // Rm[i*D+j] = w_res[j][i] + (i==j)
    int i = t & 511, j = t >> 9;
    Rm[(size_t)i * D + j] = w_res[(size_t)j * D + i] + ((i == j) ? 1.0f : 0.0f);
  }
}

// ---- L1..L3: 2-hop (blocks 0..511) | 1-hop (512..767) | fstep (768..899) --
__global__ __launch_bounds__(1024) void stage_kernel(
    const int* __restrict__ knn, const float* __restrict__ zbuf,
    const float* __restrict__ Rm, const float* __restrict__ Mt,
    const float* __restrict__ Fprev, float* __restrict__ Fnext, int first,
    const float4* __restrict__ sin, float4* __restrict__ sout1,
    float4* __restrict__ sout2) {
  const int tid = threadIdx.x;
  if (blockIdx.x < 512) {
    twohop32(blockIdx.x * 1024 + tid, knn, sin, sout2);
  } else if (blockIdx.x < 768) {
    onehop16((blockIdx.x - 512) * 1024 + tid, knn, sin, sout1);
  } else {
    fstep_block(blockIdx.x - 768, tid, first, Fprev, zbuf, Rm, Mt, Fnext);
  }
}

// ---- L4: out[n][:] = [s0..s7,1][n] x Ecat; s7 inline (1-hop from s6) ----
__global__ __launch_bounds__(1024, 4) void out_kernel(
    const int* __restrict__ knn, const float4* __restrict__ sbase,
    const float* __restrict__ Ecat, float* __restrict__ outp) {
  const int tid = threadIdx.x;
  const int n0 = blockIdx.x * 64;
  __shared__ float4 s_t[8][64];
  {  // s7 for this block's 64 points: 16 threads/point
    int pt = tid >> 4, k = tid & 15;
    float4 g = sbase[(size_t)6 * NPTS + knn[(n0 + pt) * KNB + k]];
    float4 s = redN(g.x, g.y, g.z, g.w, 16);
    if (k == 0) {
      const float r = 1.f / 16.f;
      s_t[7][pt] = make_float4(s.x * r, s.y * r, s.z * r, s.w * r);
    }
  }
  if (tid < 448) {  // load s0..s6 tiles
    int k = tid / 64, pt = tid & 63;
    s_t[k][pt] = sbase[(size_t)k * NPTS + n0 + pt];
  }
  __syncthreads();
  const int col2 = tid & 255;  // this thread's float2 column
  const int ptg = tid >> 8;    // 0..3
  float2 tab[33];
#pragma unroll
  for (int r = 0; r < 33; ++r)
    tab[r] = *(const float2*)(Ecat + r * D + col2 * 2);
#pragma unroll
  for (int it = 0; it < 16; ++it) {
    int pt = ptg * 16 + it;
    float2 acc = tab[32];
#pragma unroll
    for (int k = 0; k < 8; ++k) {
      float4 s = s_t[k][pt];  // wave-uniform LDS broadcast
      float2 e0 = tab[4 * k + 0], e1 = tab[4 * k + 1];
      float2 e2 = tab[4 * k + 2], e3 = tab[4 * k + 3];
      acc.x += s.x * e0.x + s.y * e1.x + s.z * e2.x + s.w * e3.x;
      acc.y += s.x * e0.y + s.y * e1.y + s.z * e2.y + s.w * e3.y;
    }
    *(float2*)(outp + (size_t)(n0 + pt) * D + col2 * 2) = acc;
  }
}

extern "C" void kernel_launch(void* const* d_in, const int* in_sizes, int n_in,
                              void* d_out, int out_size, void* d_ws,
                              size_t ws_size, hipStream_t stream) {
  const float* inputs = (const float*)d_in[0];
  const int* knn_raw  = (const int*)d_in[1];
  const float* w_mlp1 = (const float*)d_in[2];
  const float* b_mlp1 = (const float*)d_in[3];
  const float* w_lfa1 = (const float*)d_in[4];
  const float* b_lfa1 = (const float*)d_in[5];
  const float* w_lfa2 = (const float*)d_in[6];
  const float* b_lfa2 = (const float*)d_in[7];
  const float* w_mlp2 = (const float*)d_in[8];
  const float* b_mlp2 = (const float*)d_in[9];
  const float* w_res  = (const float*)d_in[10];
  const float* b_res  = (const float*)d_in[11];
  float* out = (float*)d_out;

  // workspace (floats): ~5.5 MB
  float*  ws    = (float*)d_ws;
  float4* sbase = (float4*)(ws + 0);          // 8 * 16384 float4
  float*  zbuf  = ws + 524288;                // 9 * 512
  float*  F2    = ws + 528896;                // 33 * 512
  float*  F3    = ws + 545792;                // 33 * 512
  float*  Ecat  = ws + 562688;                // 33 * 512
  int*    knn_i = (int*)(ws + 579584);        // 262144 ints
  float*  Mt    = ws + 841728;                // 262144 floats
  float*  Rm    = ws + 1103872;               // 262144 floats

  prep_kernel<<<1024, 256, 0, stream>>>(inputs, knn_raw, w_mlp1, b_mlp1,
                                        w_lfa1, b_lfa1, w_lfa2, b_lfa2,
                                        w_mlp2, b_mlp2, w_res, b_res,
                                        knn_i, sbase, zbuf, Mt, Rm);
  // L1: s2 = S^2 s0 | s1 = S s0 | F2 = step(F1=Cb)
  stage_kernel<<<900, 1024, 0, stream>>>(
      knn_i, zbuf, Rm, Mt, (const float*)nullptr, F2, 1, sbase,
      sbase + (size_t)1 * NPTS, sbase + (size_t)2 * NPTS);
  // L2: s4 = S^2 s2 | s3 = S s2 | F3 = step(F2)
  stage_kernel<<<900, 1024, 0, stream>>>(
      knn_i, zbuf, Rm, Mt, F2, F3, 0, sbase + (size_t)2 * NPTS,
      sbase + (size_t)3 * NPTS, sbase + (size_t)4 * NPTS);
  // L3: s6 = S^2 s4 | s5 = S s4 | Ecat = F4 = step(F3)
  stage_kernel<<<900, 1024, 0, stream>>>(
      knn_i, zbuf, Rm, Mt, F3, Ecat, 0, sbase + (size_t)4 * NPTS,
      sbase + (size_t)5 * NPTS, sbase + (size_t)6 * NPTS);
  // L4: out (s7 inline)
  out_kernel<<<256, 1024, 0, stream>>>(knn_i, sbase, Ecat, out);
}

// Round 9
// 176.398 us; speedup vs baseline: 1.2108x; 1.2108x over previous
//
#include <hip/hip_runtime.h>
#include <math.h>

#define NPTS 16384
#define KNB  16
#define D    512

// ---------------------------------------------------------------------------
// Closed-form restructure (verified rounds 1-8, absmax 0.0625). With
// S = gather-mean, R = Wres^T + I, M' = (W2c*W1)^T, per-block map
// f' = Cb + S^2 f M' + f R (f0 = 0), tracked in [33,512] coefficient space
// (rows 4k+c = component c of s_k, row 32 = bias):
//   F_1 = Cb33,   F_{t+1} = Cb33 + Shift2(F_t)*M' + F_t*R,   Ecat = F_4
// Final: out = [s0..s7,1] ([N,33]) x Ecat.
// Round 9: all-1-hop s-chain (7 serial hops, ~0.26M leaf requests each)
// replaces the 2-hop composition (4.2M leaf requests each) — launch gaps
// measured cheap (~2.5us) so trading +3 dispatches for 7.4x less scattered
// traffic. fstep1/2/3 ride along in H1/H3/H5 as extra blocks.
// ---------------------------------------------------------------------------

__device__ __forceinline__ float4 red16(float ax, float ay, float az,
                                        float aw) {
#pragma unroll
  for (int o = 1; o < 16; o <<= 1) {
    ax += __shfl_xor(ax, o, 64); ay += __shfl_xor(ay, o, 64);
    az += __shfl_xor(az, o, 64); aw += __shfl_xor(aw, o, 64);
  }
  return make_float4(ax, ay, az, aw);
}

// 1-hop gather-mean, 16 threads/point (t < 262144)
__device__ __forceinline__ void onehop16(int t, const int* __restrict__ knn,
                                         const float4* __restrict__ in,
                                         float4* __restrict__ out) {
  int n = t >> 4, k = t & 15;
  float4 g = in[knn[n * KNB + k]];
  float4 s = red16(g.x, g.y, g.z, g.w);
  if (k == 0) {
    const float r = 1.f / 16.f;
    out[n] = make_float4(s.x * r, s.y * r, s.z * r, s.w * r);
  }
}

// One Horner step: Fnext[r][j] = cb(r,j) + sum_k Fprev[r][k]R[k][j]
//                               + sum_k Fprev[rm][k]M'[k][j]
// rm = r-8 (rows 8..31), 32 for bias row, none for rows 0..7.
// rb in [0,132): r = rb>>2, col-chunk = rb&3. 1024 thr: 128 cols x 8 k-chunks.
__device__ __forceinline__ void fstep_block(
    int rb, int tid, int first, const float* __restrict__ Fprev,
    const float* __restrict__ zbuf, const float* __restrict__ Rm,
    const float* __restrict__ Mt, float* __restrict__ Fnext) {
  __shared__ double sA[512], sB[512];
  __shared__ double red[8][128];
  const int r = rb >> 2, cchunk = rb & 3;
  const int rm = (r >= 8 && r < 32) ? (r - 8) : (r == 32 ? 32 : -1);
  if (tid < 512) {
    float v;
    if (first)
      v = (r < 8) ? zbuf[r * D + tid] : (r == 32 ? zbuf[8 * D + tid] : 0.f);
    else
      v = Fprev[r * D + tid];
    sA[tid] = (double)v;
  } else {
    int kk = tid - 512;
    float v = 0.f;
    if (rm >= 0) {
      if (first)
        v = (rm < 8) ? zbuf[rm * D + kk] : (rm == 32 ? zbuf[8 * D + kk] : 0.f);
      else
        v = Fprev[rm * D + kk];
    }
    sB[kk] = (double)v;
  }
  __syncthreads();
  const int col = tid & 127, kc = tid >> 7;
  const int j = cchunk * 128 + col, k0 = kc * 64;
  double a0 = 0.0, a1 = 0.0;
  for (int k = 0; k < 64; k += 2) {
    a0 += sA[k0 + k] * (double)Rm[(size_t)(k0 + k) * D + j] +
          sB[k0 + k] * (double)Mt[(size_t)(k0 + k) * D + j];
    a1 += sA[k0 + k + 1] * (double)Rm[(size_t)(k0 + k + 1) * D + j] +
          sB[k0 + k + 1] * (double)Mt[(size_t)(k0 + k + 1) * D + j];
  }
  red[kc][col] = a0 + a1;
  __syncthreads();
  if (kc == 0) {
    double s = 0.0;
#pragma unroll
    for (int u = 0; u < 8; ++u) s += red[u][col];
    float cb = (r < 8) ? zbuf[r * D + j] : (r == 32 ? zbuf[8 * D + j] : 0.f);
    Fnext[r * D + j] = (float)(s + (double)cb);
  }
}

// ---- L0: knn normalize | geo (16 thr/pt) | pq(z) | Mt | Rm ----
__global__ __launch_bounds__(256) void prep_kernel(
    const float* __restrict__ pts, const int* __restrict__ raw,
    const float* __restrict__ w_mlp1, const float* __restrict__ b_mlp1,
    const float* __restrict__ w_lfa1, const float* __restrict__ b_lfa1,
    const float* __restrict__ w_lfa2, const float* __restrict__ b_lfa2,
    const float* __restrict__ w_mlp2, const float* __restrict__ b_mlp2,
    const float* __restrict__ w_res, const float* __restrict__ b_res,
    int* __restrict__ knn_i, float4* __restrict__ sbase,
    float* __restrict__ zbuf, float* __restrict__ Mt,
    float* __restrict__ Rm) {
  // int64 little-endian => odd words are zero high halves; (1/16384)^4 FP risk
  const bool is64 = (raw[1] == 0) && (raw[3] == 0) && (raw[5] == 0) &&
                    (raw[7] == 0);
  const int t = blockIdx.x * 256 + threadIdx.x;  // < 262144 == D*D
  knn_i[t] = is64 ? raw[2 * t] : raw[t];
  {  // geo: 16 threads/point
    int n = t >> 4, k = t & 15;
    int idx = is64 ? raw[2 * (n * KNB + k)] : raw[n * KNB + k];
    float dx = pts[n * 3 + 0] - pts[idx * 3 + 0];
    float dy = pts[n * 3 + 1] - pts[idx * 3 + 1];
    float dz = pts[n * 3 + 2] - pts[idx * 3 + 2];
    float nr = sqrtf(dx * dx + dy * dy + dz * dz);
    float4 s = red16(dx, dy, dz, nr);
    if (k == 0) {
      const float r = 1.f / 16.f;
      sbase[n] = make_float4(s.x * r, s.y * r, s.z * r, s.w * r);
    }
  }
  if (t < 32768) {  // pq: one wave per output column j; fp64 accumulate
    int j = t >> 6, lane = t & 63;
    const float* wrow = w_mlp2 + (size_t)j * D;
    double acc[9];
#pragma unroll
    for (int u = 0; u < 9; ++u) acc[u] = 0.0;
#pragma unroll
    for (int it = 0; it < 8; ++it) {
      int i = lane + 64 * it;
      double w = wrow[i];
      if (i < 256) {
        acc[0] += w * w_lfa2[i * 4 + 0]; acc[1] += w * w_lfa2[i * 4 + 1];
        acc[2] += w * w_lfa2[i * 4 + 2]; acc[3] += w * w_lfa2[i * 4 + 3];
        acc[8] += w * b_lfa2[i];
      } else if (i < 384) {
        int q = i - 256;
        acc[4] += w * w_lfa1[q * 4 + 0]; acc[5] += w * w_lfa1[q * 4 + 1];
        acc[6] += w * w_lfa1[q * 4 + 2]; acc[7] += w * w_lfa1[q * 4 + 3];
        acc[8] += w * b_lfa1[q];
      } else {
        acc[8] += w * b_mlp1[i - 384];
      }
    }
#pragma unroll
    for (int u = 0; u < 9; ++u) {
      double v = acc[u];
#pragma unroll
      for (int o = 32; o > 0; o >>= 1) v += __shfl_down(v, o, 64);
      if (lane == 0) {
        if (u == 8) v += (double)b_mlp2[j] + (double)b_res[j];
        zbuf[u * D + j] = (float)v;
      }
    }
  }
  {  // Mt[a*D+b] = sum_{i<128} w_mlp2[b][384+i]*w_mlp1[i][a]  (fp64 acc)
    int a = t & 511, b = t >> 9;
    const float* wrow = w_mlp2 + (size_t)b * D + 384;
    double s0 = 0.0, s1 = 0.0, s2 = 0.0, s3 = 0.0;
#pragma unroll 8
    for (int i = 0; i < 128; i += 4) {
      s0 += (double)wrow[i + 0] * (double)w_mlp1[(size_t)(i + 0) * D + a];
      s1 += (double)wrow[i + 1] * (double)w_mlp1[(size_t)(i + 1) * D + a];
      s2 += (double)wrow[i + 2] * (double)w_mlp1[(size_t)(i + 2) * D + a];
      s3 += (double)wrow[i + 3] * (double)w_mlp1[(size_t)(i + 3) * D + a];
    }
    Mt[(size_t)a * D + b] = (float)((s0 + s1) + (s2 + s3));
  }
  {  // Rm[i*D+j] = w_res[j][i] + (i==j)
    int i = t & 511, j = t >> 9;
    Rm[(size_t)i * D + j] = w_res[(size_t)j * D + i] + ((i == j) ? 1.0f : 0.0f);
  }
}

// ---- H1..H6: 1-hop (blocks 0..255) | optional fstep (blocks 256..387) ----
__global__ __launch_bounds__(1024) void hop_kernel(
    const int* __restrict__ knn, const float4* __restrict__ sin,
    float4* __restrict__ sout, const float* __restrict__ zbuf,
    const float* __restrict__ Rm, const float* __restrict__ Mt,
    const float* __restrict__ Fprev, float* __restrict__ Fnext, int first) {
  const int tid = threadIdx.x;
  if (blockIdx.x < 256) {
    onehop16(blockIdx.x * 1024 + tid, knn, sin, sout);
  } else {
    fstep_block(blockIdx.x - 256, tid, first, Fprev, zbuf, Rm, Mt, Fnext);
  }
}

// ---- L4: out[n][:] = [s0..s7,1][n] x Ecat; s7 inline (1-hop from s6) ----
__global__ __launch_bounds__(1024, 4) void out_kernel(
    const int* __restrict__ knn, const float4* __restrict__ sbase,
    const float* __restrict__ Ecat, float* __restrict__ outp) {
  const int tid = threadIdx.x;
  const int n0 = blockIdx.x * 64;
  __shared__ float4 s_t[8][64];
  {  // s7 for this block's 64 points: 16 threads/point
    int pt = tid >> 4, k = tid & 15;
    float4 g = sbase[(size_t)6 * NPTS + knn[(n0 + pt) * KNB + k]];
    float4 s = red16(g.x, g.y, g.z, g.w);
    if (k == 0) {
      const float r = 1.f / 16.f;
      s_t[7][pt] = make_float4(s.x * r, s.y * r, s.z * r, s.w * r);
    }
  }
  if (tid < 448) {  // load s0..s6 tiles
    int k = tid / 64, pt = tid & 63;
    s_t[k][pt] = sbase[(size_t)k * NPTS + n0 + pt];
  }
  __syncthreads();
  const int col2 = tid & 255;  // this thread's float2 column
  const int ptg = tid >> 8;    // 0..3
  float2 tab[33];
#pragma unroll
  for (int r = 0; r < 33; ++r)
    tab[r] = *(const float2*)(Ecat + r * D + col2 * 2);
#pragma unroll
  for (int it = 0; it < 16; ++it) {
    int pt = ptg * 16 + it;
    float2 acc = tab[32];
#pragma unroll
    for (int k = 0; k < 8; ++k) {
      float4 s = s_t[k][pt];  // wave-uniform LDS broadcast
      float2 e0 = tab[4 * k + 0], e1 = tab[4 * k + 1];
      float2 e2 = tab[4 * k + 2], e3 = tab[4 * k + 3];
      acc.x += s.x * e0.x + s.y * e1.x + s.z * e2.x + s.w * e3.x;
      acc.y += s.x * e0.y + s.y * e1.y + s.z * e2.y + s.w * e3.y;
    }
    *(float2*)(outp + (size_t)(n0 + pt) * D + col2 * 2) = acc;
  }
}

extern "C" void kernel_launch(void* const* d_in, const int* in_sizes, int n_in,
                              void* d_out, int out_size, void* d_ws,
                              size_t ws_size, hipStream_t stream) {
  const float* inputs = (const float*)d_in[0];
  const int* knn_raw  = (const int*)d_in[1];
  const float* w_mlp1 = (const float*)d_in[2];
  const float* b_mlp1 = (const float*)d_in[3];
  const float* w_lfa1 = (const float*)d_in[4];
  const float* b_lfa1 = (const float*)d_in[5];
  const float* w_lfa2 = (const float*)d_in[6];
  const float* b_lfa2 = (const float*)d_in[7];
  const float* w_mlp2 = (const float*)d_in[8];
  const float* b_mlp2 = (const float*)d_in[9];
  const float* w_res  = (const float*)d_in[10];
  const float* b_res  = (const float*)d_in[11];
  float* out = (float*)d_out;

  // workspace (floats): ~5.5 MB
  float*  ws    = (float*)d_ws;
  float4* sbase = (float4*)(ws + 0);          // 8 * 16384 float4
  float*  zbuf  = ws + 524288;                // 9 * 512
  float*  F2    = ws + 528896;                // 33 * 512
  float*  F3    = ws + 545792;                // 33 * 512
  float*  Ecat  = ws + 562688;                // 33 * 512
  int*    knn_i = (int*)(ws + 579584);        // 262144 ints
  float*  Mt    = ws + 841728;                // 262144 floats
  float*  Rm    = ws + 1103872;               // 262144 floats

  prep_kernel<<<1024, 256, 0, stream>>>(inputs, knn_raw, w_mlp1, b_mlp1,
                                        w_lfa1, b_lfa1, w_lfa2, b_lfa2,
                                        w_mlp2, b_mlp2, w_res, b_res,
                                        knn_i, sbase, zbuf, Mt, Rm);
  float4* s0 = (float4*)sbase;
  // H1: s1 = S s0 | fstep1: F2 = step(Cb)
  hop_kernel<<<388, 1024, 0, stream>>>(knn_i, s0, s0 + NPTS, zbuf, Rm, Mt,
                                       (const float*)nullptr, F2, 1);
  // H2: s2 = S s1
  hop_kernel<<<256, 1024, 0, stream>>>(knn_i, s0 + NPTS, s0 + 2 * NPTS, zbuf,
                                       Rm, Mt, (const float*)nullptr,
                                       (float*)nullptr, 0);
  // H3: s3 = S s2 | fstep2: F3 = step(F2)
  hop_kernel<<<388, 1024, 0, stream>>>(knn_i, s0 + 2 * NPTS, s0 + 3 * NPTS,
                                       zbuf, Rm, Mt, F2, F3, 0);
  // H4: s4 = S s3
  hop_kernel<<<256, 1024, 0, stream>>>(knn_i, s0 + 3 * NPTS, s0 + 4 * NPTS,
                                       zbuf, Rm, Mt, (const float*)nullptr,
                                       (float*)nullptr, 0);
  // H5: s5 = S s4 | fstep3: Ecat = F4 = step(F3)
  hop_kernel<<<388, 1024, 0, stream>>>(knn_i, s0 + 4 * NPTS, s0 + 5 * NPTS,
                                       zbuf, Rm, Mt, F3, Ecat, 0);
  // H6: s6 = S s5
  hop_kernel<<<256, 1024, 0, stream>>>(knn_i, s0 + 5 * NPTS, s0 + 6 * NPTS,
                                       zbuf, Rm, Mt, (const float*)nullptr,
                                       (float*)nullptr, 0);
  // L4: out (s7 inline)
  out_kernel<<<256, 1024, 0, stream>>>(knn_i, sbase, Ecat, out);
}